// Round 1
// baseline (1202.804 us; speedup 1.0000x reference)
//
#include <hip/hip_runtime.h>

// Fused attention layer (B*D=64, N=1024, d_in=192, d_model=512), fp32 in/out.
// Strategy: no fp32 MFMA on CDNA4 -> split-fp16 3-term MFMA (hi*hi+hi*lo+lo*hi,
// fp32 accum) for QKV projection and QK^T (logit err ~1e-4 despite T=0.05
// amplification); single-fp16 MFMA for A@V (err ~2e-3 absmax).
// 5 kernels: prep_w -> qkv_proj -> scores(+mask, logits into d_out A region)
// -> softmax in place (+ fp16 A copy into ws, aliasing dead q buffers) -> PV.

typedef _Float16 f16;
typedef f16 f16x8 __attribute__((ext_vector_type(8)));
typedef f16 f16x4 __attribute__((ext_vector_type(4)));
typedef float f32x4 __attribute__((ext_vector_type(4)));

constexpr int NB  = 64;    // B*D batches
constexpr int N   = 1024;  // tokens
constexpr int DIN = 192;   // 2*seq_len
constexpr int DM  = 512;   // d_model
constexpr float SCALE_T      = 0.8838834764831844f;   // (1/sqrt(512))/0.05
constexpr float MASKED_LOGIT = -460.51701859880914f;  // -ln(1e10)/0.05

__device__ __forceinline__ f32x4 mfma16(f16x8 a, f16x8 b, f32x4 c) {
  return __builtin_amdgcn_mfma_f32_16x16x32_f16(a, b, c, 0, 0, 0);
}

typedef const __attribute__((address_space(1))) void gv_t;
typedef __attribute__((address_space(3))) void lv_t;
__device__ __forceinline__ void gl_lds16(const void* g, void* l) {
  __builtin_amdgcn_global_load_lds((gv_t*)g, (lv_t*)l, 16, 0, 0);
}

// ---------------- kernel 0: split W into fp16 hi/lo, transposed [n][k] ------
__global__ void prep_w(const float* __restrict__ Wq, const float* __restrict__ Wk,
                       const float* __restrict__ Wv, f16* __restrict__ wsp) {
  int idx = blockIdx.x * 256 + threadIdx.x;
  if (idx >= 3 * DIN * DM) return;
  int w = idx / (DIN * DM);
  int rem = idx % (DIN * DM);
  int k = rem / DM, n = rem % DM;
  const float* W = (w == 0) ? Wq : (w == 1) ? Wk : Wv;
  float val = W[rem];
  f16 h = (f16)val;
  f16 l = (f16)(val - (float)h);
  f16* base = wsp + (size_t)w * 2 * DIN * DM;
  base[n * DIN + k] = h;
  base[DIN * DM + n * DIN + k] = l;
}

// ---------------- kernel 1: QKV projection, split-fp16 3-term ---------------
// grid (M/64, DM/128, 3); z selects (Wq,Wk,Wv). Writes qh/ql, kh/kl, vhT.
__global__ __launch_bounds__(256, 2) void qkv_proj(
    const float* __restrict__ x, const f16* __restrict__ wsp,
    const float* __restrict__ bq, const float* __restrict__ bk,
    const float* __restrict__ bv,
    f16* __restrict__ qh, f16* __restrict__ ql,
    f16* __restrict__ kh, f16* __restrict__ kl,
    f16* __restrict__ vhT) {
  const int z = blockIdx.z;
  const int row0 = blockIdx.x * 64;
  const int col0 = blockIdx.y * 128;
  const f16* WhT = wsp + (size_t)z * 2 * DIN * DM;
  const f16* WlT = WhT + DIN * DM;
  const float* bias = (z == 0) ? bq : (z == 1) ? bk : bv;

  __shared__ f16 xh[64 * 200];  // +8 pad per row: 2-way-max bank conflicts
  __shared__ f16 xl[64 * 200];

  const int tid = threadIdx.x;
  // stage 64x192 f32 tile, split to hi/lo fp16 on the fly
  const float4* x4 = (const float4*)x + (size_t)row0 * 48;
  #pragma unroll
  for (int it = 0; it < 12; ++it) {
    int idx = it * 256 + tid;          // 0..3071 float4s
    int r = idx / 48, c4 = idx % 48;
    float4 v = x4[(size_t)r * 48 + c4];
    f16 h0 = (f16)v.x, h1 = (f16)v.y, h2 = (f16)v.z, h3 = (f16)v.w;
    f16 l0 = (f16)(v.x - (float)h0), l1 = (f16)(v.y - (float)h1);
    f16 l2 = (f16)(v.z - (float)h2), l3 = (f16)(v.w - (float)h3);
    f16x4 th = {h0, h1, h2, h3};
    f16x4 tl = {l0, l1, l2, l3};
    *(f16x4*)&xh[r * 200 + c4 * 4] = th;
    *(f16x4*)&xl[r * 200 + c4 * 4] = tl;
  }
  __syncthreads();

  const int wid = tid >> 6, lane = tid & 63;
  const int wm = wid & 1, wn = wid >> 1;     // 2x2 waves, each 32x64
  const int lr = lane & 15, lk = lane >> 4;

  f32x4 acc[2][4] = {};
  #pragma unroll
  for (int ks = 0; ks < 6; ++ks) {           // K=192 in 6 steps of 32
    int k = ks * 32 + lk * 8;
    f16x8 ah[2], al[2], bh[4], bl[4];
    #pragma unroll
    for (int mt = 0; mt < 2; ++mt) {
      int r = wm * 32 + mt * 16 + lr;
      ah[mt] = *(const f16x8*)&xh[r * 200 + k];
      al[mt] = *(const f16x8*)&xl[r * 200 + k];
    }
    #pragma unroll
    for (int nt = 0; nt < 4; ++nt) {
      int n = col0 + wn * 64 + nt * 16 + lr;
      bh[nt] = *(const f16x8*)&WhT[n * DIN + k];   // W^T: contiguous 16B
      bl[nt] = *(const f16x8*)&WlT[n * DIN + k];
    }
    #pragma unroll
    for (int mt = 0; mt < 2; ++mt)
      #pragma unroll
      for (int nt = 0; nt < 4; ++nt) {
        acc[mt][nt] = mfma16(ah[mt], bh[nt], acc[mt][nt]);
        acc[mt][nt] = mfma16(ah[mt], bl[nt], acc[mt][nt]);
        acc[mt][nt] = mfma16(al[mt], bh[nt], acc[mt][nt]);
      }
  }
  // epilogue: +bias, split to hi/lo (q,k) or write V^T (v)
  #pragma unroll
  for (int mt = 0; mt < 2; ++mt) {
    #pragma unroll
    for (int nt = 0; nt < 4; ++nt) {
      int gcol = col0 + wn * 64 + nt * 16 + lr;
      float bval = bias[gcol];
      if (z == 2) {
        int grow0 = row0 + wm * 32 + mt * 16 + lk * 4;
        int b = grow0 >> 10, ri = grow0 & 1023;
        f16x4 t;
        #pragma unroll
        for (int r = 0; r < 4; ++r) t[r] = (f16)(acc[mt][nt][r] + bval);
        *(f16x4*)&vhT[((size_t)b * DM + gcol) * N + ri] = t;
      } else {
        #pragma unroll
        for (int r = 0; r < 4; ++r) {
          int grow = row0 + wm * 32 + mt * 16 + lk * 4 + r;
          float val = acc[mt][nt][r] + bval;
          f16 h = (f16)val;
          f16 l = (f16)(val - (float)h);
          if (z == 0) {
            qh[(size_t)grow * DM + gcol] = h;
            ql[(size_t)grow * DM + gcol] = l;
          } else {
            kh[(size_t)grow * DM + gcol] = h;
            kl[(size_t)grow * DM + gcol] = l;
          }
        }
      }
    }
  }
}

// ---------------- kernel 2: scores = mask(QK^T * scale / T) -----------------
// grid (8,8,64); 128x128 tile per block, 3-term split-fp16, K=512.
__global__ __launch_bounds__(256, 2) void scores_k(
    const f16* __restrict__ qh, const f16* __restrict__ ql,
    const f16* __restrict__ kh, const f16* __restrict__ kl,
    const float* __restrict__ mask, float* __restrict__ Aout) {
  const int z = blockIdx.z;
  const int i0 = blockIdx.x * 128, j0 = blockIdx.y * 128;

  __shared__ f16 sQh[128 * 32], sQl[128 * 32], sKh[128 * 32], sKl[128 * 32];

  const int tid = threadIdx.x;
  const int wid = tid >> 6, lane = tid & 63;
  const int wm = wid & 1, wn = wid >> 1;     // each wave: 64x64
  const int lr = lane & 15, lk = lane >> 4;

  const f16* gq  = qh + ((size_t)(z * N + i0)) * DM;
  const f16* gqL = ql + ((size_t)(z * N + i0)) * DM;
  const f16* gk  = kh + ((size_t)(z * N + j0)) * DM;
  const f16* gkL = kl + ((size_t)(z * N + j0)) * DM;

  f32x4 acc[4][4] = {};
  for (int ks = 0; ks < 16; ++ks) {          // K=512, BK=32
    __syncthreads();
    int kbase = ks * 32;
    #pragma unroll
    for (int q = 0; q < 2; ++q) {
      int slot = q * 256 + tid;
      int r = slot >> 2, c = slot & 3;
      size_t go = (size_t)r * DM + kbase + c * 8;
      int lb = (q * 256 + wid * 64) * 8;     // wave-uniform LDS base (halfs)
      gl_lds16(gq  + go, &sQh[lb]);
      gl_lds16(gqL + go, &sQl[lb]);
      gl_lds16(gk  + go, &sKh[lb]);
      gl_lds16(gkL + go, &sKl[lb]);
    }
    __syncthreads();
    f16x8 ah[4], al[4], bh[4], bl[4];
    #pragma unroll
    for (int t = 0; t < 4; ++t) {
      int ar = wm * 64 + t * 16 + lr;
      ah[t] = *(const f16x8*)&sQh[ar * 32 + lk * 8];
      al[t] = *(const f16x8*)&sQl[ar * 32 + lk * 8];
      int br = wn * 64 + t * 16 + lr;
      bh[t] = *(const f16x8*)&sKh[br * 32 + lk * 8];
      bl[t] = *(const f16x8*)&sKl[br * 32 + lk * 8];
    }
    #pragma unroll
    for (int mt = 0; mt < 4; ++mt)
      #pragma unroll
      for (int nt = 0; nt < 4; ++nt) {
        acc[mt][nt] = mfma16(ah[mt], bh[nt], acc[mt][nt]);
        acc[mt][nt] = mfma16(ah[mt], bl[nt], acc[mt][nt]);
        acc[mt][nt] = mfma16(al[mt], bh[nt], acc[mt][nt]);
      }
  }
  float* Az = Aout + (size_t)z * N * N;
  #pragma unroll
  for (int mt = 0; mt < 4; ++mt)
    #pragma unroll
    for (int nt = 0; nt < 4; ++nt)
      #pragma unroll
      for (int r = 0; r < 4; ++r) {
        int ii = i0 + wm * 64 + mt * 16 + lk * 4 + r;
        int jj = j0 + wn * 64 + nt * 16 + lr;
        float m = mask[(size_t)ii * N + jj];
        Az[(size_t)ii * N + jj] =
            (m == 0.0f) ? MASKED_LOGIT : acc[mt][nt][r] * SCALE_T;
      }
}

// ---------------- kernel 3: row softmax in place + fp16 copy ----------------
__global__ __launch_bounds__(256) void softmax_k(float* __restrict__ A,
                                                 f16* __restrict__ Ah) {
  const size_t row = blockIdx.x;
  float* p = A + row * (size_t)N;
  const int tid = threadIdx.x;
  const int wid = tid >> 6, lane = tid & 63;
  float4 v = ((float4*)p)[tid];
  float mx = fmaxf(fmaxf(v.x, v.y), fmaxf(v.z, v.w));
  #pragma unroll
  for (int o = 32; o > 0; o >>= 1) mx = fmaxf(mx, __shfl_xor(mx, o));
  __shared__ float red[4], red2[4];
  if (lane == 0) red[wid] = mx;
  __syncthreads();
  mx = fmaxf(fmaxf(red[0], red[1]), fmaxf(red[2], red[3]));
  float e0 = __expf(v.x - mx), e1 = __expf(v.y - mx);
  float e2 = __expf(v.z - mx), e3 = __expf(v.w - mx);
  float s = e0 + e1 + e2 + e3;
  #pragma unroll
  for (int o = 32; o > 0; o >>= 1) s += __shfl_xor(s, o);
  if (lane == 0) red2[wid] = s;
  __syncthreads();
  s = red2[0] + red2[1] + red2[2] + red2[3];
  float inv = 1.0f / s;
  e0 *= inv; e1 *= inv; e2 *= inv; e3 *= inv;
  float4 o4 = {e0, e1, e2, e3};
  ((float4*)p)[tid] = o4;
  f16x4 t = {(f16)e0, (f16)e1, (f16)e2, (f16)e3};
  *(f16x4*)&Ah[row * (size_t)N + tid * 4] = t;
}

// ---------------- kernel 4: output = A @ V (fp16 MFMA) ----------------------
// grid (8,4,64); 128x128 tile, K=1024 over attention dim; V consumed as V^T.
__global__ __launch_bounds__(256, 2) void pv_k(const f16* __restrict__ Ah,
                                               const f16* __restrict__ vhT,
                                               float* __restrict__ out) {
  const int z = blockIdx.z;
  const int i0 = blockIdx.x * 128, d0 = blockIdx.y * 128;
  __shared__ f16 sA[128 * 32], sV[128 * 32];
  const int tid = threadIdx.x;
  const int wid = tid >> 6, lane = tid & 63;
  const int wm = wid & 1, wn = wid >> 1;
  const int lr = lane & 15, lk = lane >> 4;
  const f16* ga = Ah  + ((size_t)(z * N + i0)) * N;
  const f16* gv = vhT + ((size_t)(z * DM + d0)) * N;
  f32x4 acc[4][4] = {};
  for (int ks = 0; ks < 32; ++ks) {          // K=1024, BK=32
    __syncthreads();
    int m0 = ks * 32;
    #pragma unroll
    for (int q = 0; q < 2; ++q) {
      int slot = q * 256 + tid;
      int r = slot >> 2, c = slot & 3;
      int lb = (q * 256 + wid * 64) * 8;
      gl_lds16(ga + (size_t)r * N + m0 + c * 8, &sA[lb]);
      gl_lds16(gv + (size_t)r * N + m0 + c * 8, &sV[lb]);
    }
    __syncthreads();
    f16x8 af[4], bf[4];
    #pragma unroll
    for (int t = 0; t < 4; ++t) {
      af[t] = *(const f16x8*)&sA[(wm * 64 + t * 16 + lr) * 32 + lk * 8];
      bf[t] = *(const f16x8*)&sV[(wn * 64 + t * 16 + lr) * 32 + lk * 8];
    }
    #pragma unroll
    for (int mt = 0; mt < 4; ++mt)
      #pragma unroll
      for (int nt = 0; nt < 4; ++nt)
        acc[mt][nt] = mfma16(af[mt], bf[nt], acc[mt][nt]);
  }
  float* oz = out + (size_t)z * N * DM;
  #pragma unroll
  for (int mt = 0; mt < 4; ++mt)
    #pragma unroll
    for (int nt = 0; nt < 4; ++nt)
      #pragma unroll
      for (int r = 0; r < 4; ++r) {
        int ii = i0 + wm * 64 + mt * 16 + lk * 4 + r;
        int dd = d0 + wn * 64 + nt * 16 + lr;
        oz[(size_t)ii * DM + dd] = acc[mt][nt][r];
      }
}

// ---------------------------------------------------------------------------
extern "C" void kernel_launch(void* const* d_in, const int* in_sizes, int n_in,
                              void* d_out, int out_size, void* d_ws,
                              size_t ws_size, hipStream_t stream) {
  (void)in_sizes; (void)n_in; (void)out_size; (void)ws_size;
  const float* x    = (const float*)d_in[0];
  const float* mask = (const float*)d_in[1];
  const float* Wq   = (const float*)d_in[2];
  const float* bq   = (const float*)d_in[3];
  const float* Wk   = (const float*)d_in[4];
  const float* bk   = (const float*)d_in[5];
  const float* Wv   = (const float*)d_in[6];
  const float* bv   = (const float*)d_in[7];

  float* out  = (float*)d_out;                       // [64,1024,512]
  float* Aout = out + (size_t)NB * N * DM;           // [64,1024,1024]

  f16* f = (f16*)d_ws;
  const size_t S = (size_t)NB * N * DM;              // 33,554,432 halfs
  f16* qh  = f;
  f16* ql  = f + S;
  f16* kh  = f + 2 * S;
  f16* kl  = f + 3 * S;
  f16* vhT = f + 4 * S;
  f16* Ah  = f;                 // aliases qh/ql (dead after scores_k) — 2S halfs
  f16* wsp = f + 5 * S;         // W hi/lo transposed, 6*98304 halfs
  // total ws need: (5S + 6*DIN*DM)*2 bytes ≈ 321 MiB

  prep_w<<<dim3((3 * DIN * DM + 255) / 256), 256, 0, stream>>>(Wq, Wk, Wv, wsp);
  qkv_proj<<<dim3(NB * N / 64, DM / 128, 3), 256, 0, stream>>>(
      x, wsp, bq, bk, bv, qh, ql, kh, kl, vhT);
  scores_k<<<dim3(N / 128, N / 128, NB), 256, 0, stream>>>(
      qh, ql, kh, kl, mask, Aout);
  softmax_k<<<dim3(NB * N), 256, 0, stream>>>(Aout, Ah);
  pv_k<<<dim3(N / 128, DM / 128, NB), 256, 0, stream>>>(Ah, vhT, out);
}